// Round 8
// baseline (696.654 us; speedup 1.0000x reference)
//
#include <hip/hip_runtime.h>

#define BB 128
#define NN 1152
#define KD 512
#define NC 10
#define ND 16
#define CD 160   // NC*ND

typedef unsigned short ushort_t;
typedef unsigned int uint_t;
typedef short short8v __attribute__((ext_vector_type(8)));
typedef float float4v __attribute__((ext_vector_type(4)));

__device__ __forceinline__ float bf2f(ushort_t u) {
  return __uint_as_float(((uint_t)u) << 16);
}
__device__ __forceinline__ ushort_t f2bf(float f) {
  uint_t x = __float_as_uint(f);
  x += 0x7fffu + ((x >> 16) & 1u);   // round-to-nearest-even
  return (ushort_t)(x >> 16);
}

// ---------- W transpose+convert: Wt[n][k] = bf16(W[k][n]), [160][512] ----------
__global__ __launch_bounds__(256) void wconv(const float* __restrict__ W,
                                             ushort_t* __restrict__ Wt) {
  int idx = blockIdx.x * 256 + threadIdx.x;   // 81920 total
  int n = idx >> 9, k = idx & 511;
  Wt[idx] = f2bf(W[(size_t)k * CD + n]);
}

// ---------- Persistent-B GEMM: B fully in LDS, ZERO barriers in stream loop ----
// Grid 256 x 1024 thr (16 waves, 4/SIMD, 1 block/CU). B = Wt bf16 [160][512]
// = 163840 B LDS, staged once (1 __syncthreads), then each wave independently
// streams 32-row units: per 16-row strip, 16 k-steps of
// {2 global float4 loads + cvt + 10 swizzled ds_read_b128 + 10 MFMA}.
// Swizzle: byte = (row<<10) + ((slot<<4) ^ ((row&7)<<4))  -> 2-way (free).
// Units: 4608 contiguous 32-row units; wave gw takes unit gw; waves gw%8==0
// additionally take unit 4096+gw/8 (tail spread 2 waves/block).
// Epilogue per unit: uhat bf16 stores + per-unit col-sum partials pg[4608][160].
__global__ __launch_bounds__(1024, 4) void gemm_persist(
    const float* __restrict__ x, const ushort_t* __restrict__ Wt,
    ushort_t* __restrict__ uhat, float* __restrict__ pg) {
  __shared__ __align__(16) ushort_t Bs[81920];   // 163840 B = full B
  const int tid = threadIdx.x;
  const int wid = tid >> 6, lane = tid & 63;
  const int lrow = lane & 15, lg = lane >> 4;

  // ---- stage B once (coalesced 16B reads, swizzled 16B LDS writes)
#pragma unroll
  for (int i = 0; i < 10; ++i) {
    int p = tid + i * 1024;            // 10240 pieces of 16B
    int row = p >> 6, slot = p & 63;
    int byte = (row << 10) + ((slot << 4) ^ ((row & 7) << 4));
    *reinterpret_cast<short8v*>(reinterpret_cast<char*>(Bs) + byte) =
        *reinterpret_cast<const short8v*>(Wt + row * KD + slot * 8);
  }
  __syncthreads();                     // only barrier in the kernel

  const int gw = blockIdx.x * 16 + wid;          // 0..4095
  const char* Bc = reinterpret_cast<const char*>(Bs);
  const int q = (lrow & 7) << 4;
  const int bb0 = (lrow << 10) + ((lg << 4) ^ q);  // B-frag base (nt=0, ks=0)

#pragma unroll 1
  for (int uu = 0; uu < 2; ++uu) {
    int unit;
    if (uu == 0) unit = gw;
    else {
      if ((gw & 7) != 0) break;
      unit = 4096 + (gw >> 3);         // 4096..4607
    }

    float psum[10];
#pragma unroll
    for (int nt = 0; nt < 10; ++nt) psum[nt] = 0.f;

#pragma unroll 1
    for (int st = 0; st < 2; ++st) {
      const int r0 = unit * 32 + st * 16;
      const float* ap = x + (size_t)(r0 + lrow) * KD + (lg << 3);

      float4v acc[10];
#pragma unroll
      for (int nt = 0; nt < 10; ++nt)
#pragma unroll
        for (int r = 0; r < 4; ++r) acc[nt][r] = 0.f;

      float4v c0 = *reinterpret_cast<const float4v*>(ap);
      float4v c1 = *reinterpret_cast<const float4v*>(ap + 4);
#pragma unroll
      for (int ks = 0; ks < 16; ++ks) {
        // prefetch next k-step's A (in-bounds dummy reload at ks=15)
        int kn = (ks < 15) ? (ks + 1) : 15;
        float4v n0 = *reinterpret_cast<const float4v*>(ap + kn * 32);
        float4v n1 = *reinterpret_cast<const float4v*>(ap + kn * 32 + 4);
        short8v af;
#pragma unroll
        for (int e = 0; e < 4; ++e) {
          af[e] = (short)f2bf(c0[e]);
          af[e + 4] = (short)f2bf(c1[e]);
        }
        const int kx = ks << 6;
#pragma unroll
        for (int nt = 0; nt < 10; ++nt) {
          short8v bf = *reinterpret_cast<const short8v*>(
              Bc + ((bb0 + nt * 16384) ^ kx));
          acc[nt] = __builtin_amdgcn_mfma_f32_16x16x32_bf16(af, bf, acc[nt], 0, 0, 0);
        }
        c0 = n0; c1 = n1;
      }

      // ---- epilogue: uhat stores (2B, L2 write-combined) + partial col-sums
#pragma unroll
      for (int nt = 0; nt < 10; ++nt) {
#pragma unroll
        for (int r = 0; r < 4; ++r) {
          uhat[(size_t)(r0 + lg * 4 + r) * CD + nt * 16 + lrow] =
              f2bf(acc[nt][r]);
        }
        float ps = acc[nt][0] + acc[nt][1] + acc[nt][2] + acc[nt][3];
        ps += __shfl_xor(ps, 16);
        ps += __shfl_xor(ps, 32);
        psum[nt] += ps;                // valid on lg==0 lanes
      }
    }
#pragma unroll
    for (int nt = 0; nt < 10; ++nt)
      if (lg == 0) pg[(size_t)unit * CD + nt * 16 + lrow] = psum[nt];
  }
}

// ---------- reduce unit partials -> s0raw[b][160] = sum over 36 units ----------
__global__ __launch_bounds__(CD) void reduce_pg(const float* __restrict__ pg,
                                                float* __restrict__ s0raw) {
  int b = blockIdx.x, t = threadIdx.x;
  float s = 0.f;
#pragma unroll
  for (int i = 0; i < 36; ++i) s += pg[((size_t)b * 36 + i) * CD + t];
  s0raw[(size_t)b * CD + t] = s;
}

// ---------- routing iteration with fused v-computation ----------
// vv = v0 = squash(0.1*s0raw); ITER2 adds v1 = squash(sum of 9 p1 chunks).
// Phase 1: logits; Phase 1.5: softmax weights once/row; Phase 2: accumulate.
#define ITER_T 640
template <int ITER2>
__global__ __launch_bounds__(ITER_T) void iter_k(
    const ushort_t* __restrict__ uhat, const float* __restrict__ s0raw,
    const float* __restrict__ p1, float* __restrict__ pout) {
  __shared__ float bv[128][NC];        // 5120 B
  __shared__ float wv[128][NC];        // 5120 B
  __shared__ float sred[32][CD];       // 20480 B
  __shared__ float sred2[4][CD];       // 2560 B
  __shared__ float vv[CD];             // 640 B
  const int blk = blockIdx.x;
  const int b = blk / 9, ch = blk % 9;
  const int t = threadIdx.x;
  const int g = t / 20, qq = t % 20;
  const int c = qq >> 1;
  const ushort_t* ub = uhat + ((size_t)b * NN + ch * 128) * CD + qq * 8;

  // ---- prologue: vv (= v0, or v0+v1 for ITER2)
  if (t < CD) {
    float s0 = s0raw[(size_t)b * CD + t] * 0.1f;
    float ss = s0 * s0;
    ss += __shfl_xor(ss, 1); ss += __shfl_xor(ss, 2);
    ss += __shfl_xor(ss, 4); ss += __shfl_xor(ss, 8);
    float sn = sqrtf(ss) + 1e-7f;
    float v = s0 * sn / (1.f + sn * sn);
    if (ITER2) {
      float s1 = 0.f;
#pragma unroll
      for (int cc = 0; cc < 9; ++cc) s1 += p1[((size_t)b * 9 + cc) * CD + t];
      float ss1 = s1 * s1;
      ss1 += __shfl_xor(ss1, 1); ss1 += __shfl_xor(ss1, 2);
      ss1 += __shfl_xor(ss1, 4); ss1 += __shfl_xor(ss1, 8);
      float sn1 = sqrtf(ss1) + 1e-7f;
      v += s1 * sn1 / (1.f + sn1 * sn1);
    }
    vv[t] = v;
  }
  __syncthreads();

  float v0r[8];
  {
    float4v a = *reinterpret_cast<const float4v*>(&vv[qq * 8]);
    float4v bb = *reinterpret_cast<const float4v*>(&vv[qq * 8 + 4]);
#pragma unroll
    for (int e = 0; e < 4; ++e) { v0r[e] = a[e]; v0r[e + 4] = bb[e]; }
  }

  // ---- phase 1: logits
  short8v u8[4];
#pragma unroll
  for (int it = 0; it < 4; ++it) {
    int n = g + it * 32;
    u8[it] = *reinterpret_cast<const short8v*>(ub + (size_t)n * CD);
    float p = 0.f;
#pragma unroll
    for (int e = 0; e < 8; ++e) p += bf2f((ushort_t)u8[it][e]) * v0r[e];
    p += __shfl_xor(p, 1);
    if ((qq & 1) == 0) bv[n][c] = p;
  }
  __syncthreads();

  // ---- phase 1.5: softmax weights once per row
  if (t < 128) {
    float e[NC];
    float bm = bv[t][0];
#pragma unroll
    for (int cc = 1; cc < NC; ++cc) bm = fmaxf(bm, bv[t][cc]);
    float Z = 0.f;
#pragma unroll
    for (int cc = 0; cc < NC; ++cc) { e[cc] = __expf(bv[t][cc] - bm); Z += e[cc]; }
    float rz = 1.f / Z;
#pragma unroll
    for (int cc = 0; cc < NC; ++cc) wv[t][cc] = e[cc] * rz;
  }
  __syncthreads();

  // ---- phase 2: weighted accumulate
  float a[8];
#pragma unroll
  for (int e = 0; e < 8; ++e) a[e] = 0.f;
#pragma unroll
  for (int it = 0; it < 4; ++it) {
    int n = g + it * 32;
    float w = wv[n][c];
#pragma unroll
    for (int e = 0; e < 8; ++e) a[e] += w * bf2f((ushort_t)u8[it][e]);
  }
  {
    float4v lo, hi;
#pragma unroll
    for (int e = 0; e < 4; ++e) { lo[e] = a[e]; hi[e] = a[e + 4]; }
    float4v* dst = reinterpret_cast<float4v*>(&sred[g][qq * 8]);
    dst[0] = lo; dst[1] = hi;
  }
  __syncthreads();
  {
    int col = t % CD, part = t / CD;    // 640 = 4 x 160
    float s = 0.f;
#pragma unroll
    for (int g8 = 0; g8 < 8; ++g8) s += sred[part * 8 + g8][col];
    sred2[part][col] = s;
  }
  __syncthreads();
  if (t < CD) {
    pout[(size_t)blk * CD + t] =
        sred2[0][t] + sred2[1][t] + sred2[2][t] + sred2[3][t];
  }
}

// ---------- final squash ----------
__global__ __launch_bounds__(CD) void squash_out(
    const float* __restrict__ p2, float* __restrict__ outp) {
  int b = blockIdx.x, t = threadIdx.x;
  float s = 0.f;
#pragma unroll
  for (int cc = 0; cc < 9; ++cc) s += p2[((size_t)b * 9 + cc) * CD + t];
  float ss = s * s;
  ss += __shfl_xor(ss, 1); ss += __shfl_xor(ss, 2);
  ss += __shfl_xor(ss, 4); ss += __shfl_xor(ss, 8);
  float sn = sqrtf(ss) + 1e-7f;
  outp[(size_t)b * CD + t] = s * sn / (1.f + sn * sn);
}

extern "C" void kernel_launch(void* const* d_in, const int* in_sizes, int n_in,
                              void* d_out, int out_size, void* d_ws, size_t ws_size,
                              hipStream_t stream) {
  const float* x = (const float*)d_in[0];   // [128,1152,512] f32
  const float* W = (const float*)d_in[1];   // [512,160] f32
  float* out = (float*)d_out;               // [128,10,16] f32

  char* ws = (char*)d_ws;
  // Layout (50,298,880 B total, with lifetime-based aliasing):
  //   uhat  @ 0          47,185,920 B   (gemm out; read by iters)
  //   Wt    @ 47,185,920    163,840 B   (wconv out; read by gemm)
  //   s0raw @ 47,185,920     81,920 B   (ALIASES Wt; written after gemm done)
  //   pg    @ 47,349,760  2,949,120 B   (gemm unit partials; read by reduce_pg)
  //   p1    @ 47,349,760    737,280 B   (ALIASES pg; written after reduce done)
  //   p2    @ 48,087,040    737,280 B   (ALIASES pg tail)
  ushort_t* uhat  = (ushort_t*)ws;
  ushort_t* Wt    = (ushort_t*)(ws + 47185920);
  float*    s0raw = (float*)(ws + 47185920);
  float*    pg    = (float*)(ws + 47349760);
  float*    p1    = (float*)(ws + 47349760);
  float*    p2    = (float*)(ws + 48087040);

  wconv<<<320, 256, 0, stream>>>(W, Wt);
  gemm_persist<<<256, 1024, 0, stream>>>(x, Wt, uhat, pg);
  reduce_pg<<<BB, CD, 0, stream>>>(pg, s0raw);
  iter_k<0><<<1152, ITER_T, 0, stream>>>(uhat, s0raw, nullptr, p1);  // s1
  iter_k<1><<<1152, ITER_T, 0, stream>>>(uhat, s0raw, p1, p2);       // s2
  squash_out<<<BB, CD, 0, stream>>>(p2, out);                        // v2
}

// Round 9
// 126.335 us; speedup vs baseline: 5.5143x; 5.5143x over previous
//
#include <hip/hip_runtime.h>

#define BB 128
#define NN 1152
#define KD 512
#define NC 10
#define ND 16
#define CD 160   // NC*ND

typedef unsigned short ushort_t;
typedef unsigned int uint_t;
typedef short short8v __attribute__((ext_vector_type(8)));
typedef float float4v __attribute__((ext_vector_type(4)));

__device__ __forceinline__ float bf2f(ushort_t u) {
  return __uint_as_float(((uint_t)u) << 16);
}
__device__ __forceinline__ ushort_t f2bf(float f) {
  uint_t x = __float_as_uint(f);
  x += 0x7fffu + ((x >> 16) & 1u);   // round-to-nearest-even
  return (ushort_t)(x >> 16);
}

// Barrier that does NOT drain vmcnt: LDS-visibility (lgkmcnt) only.
#define BAR_LDS() do {                                   \
    __builtin_amdgcn_sched_barrier(0);                   \
    asm volatile("s_waitcnt lgkmcnt(0)" ::: "memory");   \
    __builtin_amdgcn_s_barrier();                        \
    __builtin_amdgcn_sched_barrier(0);                   \
  } while (0)

// ---------- W transpose+convert: Wt[n][k] = bf16(W[k][n]), [160][512] ----------
__global__ __launch_bounds__(256) void wconv(const float* __restrict__ W,
                                             ushort_t* __restrict__ Wt) {
  int idx = blockIdx.x * 256 + threadIdx.x;   // 81920 total
  int n = idx >> 9, k = idx & 511;
  Wt[idx] = f2bf(W[(size_t)k * CD + n]);
}

// ---------- GEMM via MFMA: BM=128, BK=64, 512 thr (8 waves) ----------
// Wave w = rows w*16..+16, all 160 cols (acc[10] f32x4 = 40 VGPR).
// Grid 1152 (147456/128), 9 blocks/batch. 8 k-steps, ONE lgkmcnt-only
// barrier per step (vmcnt never drained; reg-prefetch 2 steps ahead).
// LDS (77KB -> 2 blocks/CU = 16 waves/CU = 4 waves/SIMD):
//   A[buf] @ buf*16384 (128x64 bf16, 16KB), B[buf] @ 32768+buf*20480 (20KB),
//   sA @ 73728 ([8][160] f32, 5KB). Rows 128B, swizzle byte ^= (row&7)<<4.
// Epilogue: C repack via LDS union (Ct [128][168]) -> 16B coalesced stores.
__global__ __launch_bounds__(512, 4) void gemm_mfma(
    const float* __restrict__ x, const ushort_t* __restrict__ Wt,
    ushort_t* __restrict__ uhat, float* __restrict__ partials) {
  __shared__ __align__(16) char smem[78848];
  const int tid = threadIdx.x;
  const int wid = tid >> 6, lane = tid & 63;
  const int lrow = lane & 15, lg = lane >> 4;
  const int row0 = blockIdx.x * 128;

  float4v acc[10];
#pragma unroll
  for (int nt = 0; nt < 10; ++nt)
#pragma unroll
    for (int r = 0; r < 4; ++r) acc[nt][r] = 0.f;

  // A staging: piece f = tid + i*512 (i<2): row = f>>3 (0..127), kq = f&7
  const int ar0 = tid >> 3;              // piece 0 row
  const int akq = tid & 7;
  const int aby0 = (ar0 << 7) + ((akq << 4) ^ ((ar0 & 7) << 4));
  const int ar1 = ar0 + 64;              // piece 1 row
  const int aby1 = (ar1 << 7) + ((akq << 4) ^ ((ar1 & 7) << 4));
  // B staging: piece f = tid + i*512 (i<3, third masked): row = f>>3, slot = f&7
  int bsrc[3], bby[3];
#pragma unroll
  for (int i = 0; i < 3; ++i) {
    int f = tid + i * 512;
    int br = (f >> 3) % 160, bs = f & 7;
    bsrc[i] = br * KD + bs * 8;
    bby[i] = (br << 7) + ((bs << 4) ^ ((br & 7) << 4));
  }
  const bool b2ok = (tid + 1024) < 1280;

  float4v rA[2][2];
  short8v rB[3];

  auto LOADS = [&](int ks) {
    int k0 = ks * 64;
    const float* p0 = x + (size_t)(row0 + ar0) * KD + k0 + akq * 8;
    const float* p1 = x + (size_t)(row0 + ar1) * KD + k0 + akq * 8;
    rA[0][0] = *reinterpret_cast<const float4v*>(p0);
    rA[0][1] = *reinterpret_cast<const float4v*>(p0 + 4);
    rA[1][0] = *reinterpret_cast<const float4v*>(p1);
    rA[1][1] = *reinterpret_cast<const float4v*>(p1 + 4);
    rB[0] = *reinterpret_cast<const short8v*>(Wt + bsrc[0] + k0);
    rB[1] = *reinterpret_cast<const short8v*>(Wt + bsrc[1] + k0);
    if (b2ok) rB[2] = *reinterpret_cast<const short8v*>(Wt + bsrc[2] + k0);
  };
  auto WRITES = [&](int buf) {
    char* Ab = smem + buf * 16384;
    char* Bb = smem + 32768 + buf * 20480;
#pragma unroll
    for (int i = 0; i < 2; ++i) {
      short8v pk;
#pragma unroll
      for (int e = 0; e < 4; ++e) {
        pk[e] = (short)f2bf(rA[i][0][e]);
        pk[e + 4] = (short)f2bf(rA[i][1][e]);
      }
      *reinterpret_cast<short8v*>(Ab + (i ? aby1 : aby0)) = pk;
    }
    *reinterpret_cast<short8v*>(Bb + bby[0]) = rB[0];
    *reinterpret_cast<short8v*>(Bb + bby[1]) = rB[1];
    if (b2ok) *reinterpret_cast<short8v*>(Bb + bby[2]) = rB[2];
  };

  const int arow = wid * 16 + lrow;
  LOADS(0);
  WRITES(0);
  LOADS(1);
  BAR_LDS();                             // tile 0 visible
  int cur = 0;
  for (int ks = 0; ks < 8; ++ks) {
    const char* Ab = smem + cur * 16384;
    const char* Bb = smem + 32768 + cur * 20480;
#pragma unroll
    for (int kk = 0; kk < 2; ++kk) {
      int abyte = ((arow << 7) + kk * 64 + lg * 16) ^ ((arow & 7) << 4);
      short8v a = *reinterpret_cast<const short8v*>(Ab + abyte);
#pragma unroll
      for (int nt = 0; nt < 10; ++nt) {
        int brow = nt * 16 + lrow;
        int bbyte = ((brow << 7) + kk * 64 + lg * 16) ^ ((brow & 7) << 4);
        short8v bfr = *reinterpret_cast<const short8v*>(Bb + bbyte);
        acc[nt] = __builtin_amdgcn_mfma_f32_16x16x32_bf16(a, bfr, acc[nt], 0, 0, 0);
      }
    }
    if (ks < 7) {
      WRITES(cur ^ 1);                   // tile ks+1 -> other buf
      if (ks < 6) LOADS(ks + 2);
    }
    BAR_LDS();
    cur ^= 1;
  }

  // ---- passA partials: col-sums over this block's 128 rows
  float* sAf = reinterpret_cast<float*>(smem + 73728);   // [8][160]
#pragma unroll
  for (int nt = 0; nt < 10; ++nt) {
    float p = acc[nt][0] + acc[nt][1] + acc[nt][2] + acc[nt][3];
    p += __shfl_xor(p, 16);
    p += __shfl_xor(p, 32);
    if (lg == 0) sAf[wid * CD + nt * 16 + lrow] = p;
  }

  // ---- C repack through LDS union -> coalesced 16B stores
  ushort_t* Ct = reinterpret_cast<ushort_t*>(smem);     // [128][168] = 43008 B
#pragma unroll
  for (int nt = 0; nt < 10; ++nt)
#pragma unroll
    for (int r = 0; r < 4; ++r) {
      int row = wid * 16 + lg * 4 + r;
      Ct[row * 168 + nt * 16 + lrow] = f2bf(acc[nt][r]);
    }
  __syncthreads();
  if (tid < CD) {
    float s = 0.f;
#pragma unroll
    for (int w = 0; w < 8; ++w) s += sAf[w * CD + tid];
    partials[(size_t)blockIdx.x * CD + tid] = s;
  }
#pragma unroll
  for (int i = 0; i < 5; ++i) {
    int p = tid + i * 512;                 // 2560 pieces of 16B
    int row = p / 20, c0 = (p % 20) * 8;
    *reinterpret_cast<short8v*>(&uhat[(size_t)(row0 + row) * CD + c0]) =
        *reinterpret_cast<const short8v*>(&Ct[row * 168 + c0]);
  }
}

// ---------- routing iteration with fused v-computation ----------
// vv = v0 = squash(0.1*sum(pg 9 chunks)); ITER2 adds v1 = squash(sum(p1)).
#define ITER_T 640
template <int ITER2>
__global__ __launch_bounds__(ITER_T) void iter_k(
    const ushort_t* __restrict__ uhat, const float* __restrict__ pg,
    const float* __restrict__ p1, float* __restrict__ pout) {
  __shared__ float bv[128][NC];        // 5120 B
  __shared__ float wv[128][NC];        // 5120 B
  __shared__ float sred[32][CD];       // 20480 B
  __shared__ float sred2[4][CD];       // 2560 B
  __shared__ float vv[CD];             // 640 B
  const int blk = blockIdx.x;
  const int b = blk / 9, ch = blk % 9;
  const int t = threadIdx.x;
  const int g = t / 20, q = t % 20;
  const int c = q >> 1;
  const ushort_t* ub = uhat + ((size_t)b * NN + ch * 128) * CD + q * 8;

  // ---- prologue: compute vv (= v0, or v0+v1 for ITER2)
  if (t < CD) {
    float s0 = 0.f;
#pragma unroll
    for (int cc = 0; cc < 9; ++cc) s0 += pg[((size_t)b * 9 + cc) * CD + t];
    s0 *= 0.1f;
    float ss = s0 * s0;
    ss += __shfl_xor(ss, 1); ss += __shfl_xor(ss, 2);
    ss += __shfl_xor(ss, 4); ss += __shfl_xor(ss, 8);
    float sn = sqrtf(ss) + 1e-7f;
    float v = s0 * sn / (1.f + sn * sn);
    if (ITER2) {
      float s1 = 0.f;
#pragma unroll
      for (int cc = 0; cc < 9; ++cc) s1 += p1[((size_t)b * 9 + cc) * CD + t];
      float ss1 = s1 * s1;
      ss1 += __shfl_xor(ss1, 1); ss1 += __shfl_xor(ss1, 2);
      ss1 += __shfl_xor(ss1, 4); ss1 += __shfl_xor(ss1, 8);
      float sn1 = sqrtf(ss1) + 1e-7f;
      v += s1 * sn1 / (1.f + sn1 * sn1);
    }
    vv[t] = v;
  }
  __syncthreads();

  float v0r[8];
  {
    float4v a = *reinterpret_cast<const float4v*>(&vv[q * 8]);
    float4v bb = *reinterpret_cast<const float4v*>(&vv[q * 8 + 4]);
#pragma unroll
    for (int e = 0; e < 4; ++e) { v0r[e] = a[e]; v0r[e + 4] = bb[e]; }
  }

  // ---- phase 1: logits
  short8v u8[4];
#pragma unroll
  for (int it = 0; it < 4; ++it) {
    int n = g + it * 32;
    u8[it] = *reinterpret_cast<const short8v*>(ub + (size_t)n * CD);
    float p = 0.f;
#pragma unroll
    for (int e = 0; e < 8; ++e) p += bf2f((ushort_t)u8[it][e]) * v0r[e];
    p += __shfl_xor(p, 1);
    if ((q & 1) == 0) bv[n][c] = p;
  }
  __syncthreads();

  // ---- phase 1.5: softmax weights once per row
  if (t < 128) {
    float e[NC];
    float bm = bv[t][0];
#pragma unroll
    for (int cc = 1; cc < NC; ++cc) bm = fmaxf(bm, bv[t][cc]);
    float Z = 0.f;
#pragma unroll
    for (int cc = 0; cc < NC; ++cc) { e[cc] = __expf(bv[t][cc] - bm); Z += e[cc]; }
    float rz = 1.f / Z;
#pragma unroll
    for (int cc = 0; cc < NC; ++cc) wv[t][cc] = e[cc] * rz;
  }
  __syncthreads();

  // ---- phase 2: weighted accumulate
  float a[8];
#pragma unroll
  for (int e = 0; e < 8; ++e) a[e] = 0.f;
#pragma unroll
  for (int it = 0; it < 4; ++it) {
    int n = g + it * 32;
    float w = wv[n][c];
#pragma unroll
    for (int e = 0; e < 8; ++e) a[e] += w * bf2f((ushort_t)u8[it][e]);
  }
  {
    float4v lo, hi;
#pragma unroll
    for (int e = 0; e < 4; ++e) { lo[e] = a[e]; hi[e] = a[e + 4]; }
    float4v* dst = reinterpret_cast<float4v*>(&sred[g][q * 8]);
    dst[0] = lo; dst[1] = hi;
  }
  __syncthreads();
  {
    int col = t % CD, part = t / CD;    // 640 = 4 x 160
    float s = 0.f;
#pragma unroll
    for (int g8 = 0; g8 < 8; ++g8) s += sred[part * 8 + g8][col];
    sred2[part][col] = s;
  }
  __syncthreads();
  if (t < CD) {
    pout[(size_t)blk * CD + t] =
        sred2[0][t] + sred2[1][t] + sred2[2][t] + sred2[3][t];
  }
}

// ---------- final squash ----------
__global__ __launch_bounds__(CD) void squash_out(
    const float* __restrict__ p2, float* __restrict__ outp) {
  int b = blockIdx.x, t = threadIdx.x;
  float s = 0.f;
#pragma unroll
  for (int cc = 0; cc < 9; ++cc) s += p2[((size_t)b * 9 + cc) * CD + t];
  float ss = s * s;
  ss += __shfl_xor(ss, 1); ss += __shfl_xor(ss, 2);
  ss += __shfl_xor(ss, 4); ss += __shfl_xor(ss, 8);
  float sn = sqrtf(ss) + 1e-7f;
  outp[(size_t)b * CD + t] = s * sn / (1.f + sn * sn);
}

extern "C" void kernel_launch(void* const* d_in, const int* in_sizes, int n_in,
                              void* d_out, int out_size, void* d_ws, size_t ws_size,
                              hipStream_t stream) {
  const float* x = (const float*)d_in[0];   // [128,1152,512] f32
  const float* W = (const float*)d_in[1];   // [512,160] f32
  float* out = (float*)d_out;               // [128,10,16] f32

  char* ws = (char*)d_ws;
  ushort_t* uhat = (ushort_t*)ws;                          // 47,185,920 B
  ushort_t* Wt   = (ushort_t*)(ws + 47185920);             //    163,840 B
  float*    pg   = (float*)(ws + 47349760);                //    737,280 B  [1152][160]
  float*    p1   = (float*)(ws + 48087040);                //    737,280 B
  float*    p2   = (float*)(ws + 48824320);                //    737,280 B

  wconv<<<320, 256, 0, stream>>>(W, Wt);
  gemm_mfma<<<1152, 512, 0, stream>>>(x, Wt, uhat, pg);
  iter_k<0><<<1152, ITER_T, 0, stream>>>(uhat, pg, nullptr, p1);  // s1 partials
  iter_k<1><<<1152, ITER_T, 0, stream>>>(uhat, pg, p1, p2);       // s2 partials
  squash_out<<<BB, CD, 0, stream>>>(p2, out);                     // out = v2
}

// Round 10
// 103.086 us; speedup vs baseline: 6.7580x; 1.2255x over previous
//
#include <hip/hip_runtime.h>

#define BB 128
#define NN 1152
#define KD 512
#define NC 10
#define ND 16
#define CD 160   // NC*ND

typedef unsigned short ushort_t;
typedef unsigned int uint_t;
typedef short short8v __attribute__((ext_vector_type(8)));
typedef float float4v __attribute__((ext_vector_type(4)));
typedef float float16v __attribute__((ext_vector_type(16)));

__device__ __forceinline__ float bf2f(ushort_t u) {
  return __uint_as_float(((uint_t)u) << 16);
}
__device__ __forceinline__ ushort_t f2bf(float f) {
  uint_t x = __float_as_uint(f);
  x += 0x7fffu + ((x >> 16) & 1u);   // round-to-nearest-even
  return (ushort_t)(x >> 16);
}

// Barrier that does NOT drain vmcnt: LDS-visibility (lgkmcnt) only.
#define BAR_LDS() do {                                   \
    __builtin_amdgcn_sched_barrier(0);                   \
    asm volatile("s_waitcnt lgkmcnt(0)" ::: "memory");   \
    __builtin_amdgcn_s_barrier();                        \
    __builtin_amdgcn_sched_barrier(0);                   \
  } while (0)

// ---------- W transpose+convert: Wt[n][k] = bf16(W[k][n]), [160][512] ----------
__global__ __launch_bounds__(256) void wconv(const float* __restrict__ W,
                                             ushort_t* __restrict__ Wt) {
  int idx = blockIdx.x * 256 + threadIdx.x;   // 81920 total
  int n = idx >> 9, k = idx & 511;
  Wt[idx] = f2bf(W[(size_t)k * CD + n]);
}

// ---------- GEMM via 32x32x16 MFMA: BM=128, BK=64, 256 thr (4 waves) ----------
// Wave w = rows w*32..+32, all 160 cols as 5 tiles of 32 (acc[5] f32x16 = 80 VGPR).
// 32x32 tiles double A/B fragment reuse vs 16x16 -> LDS reads/FLOP halve.
// Grid 1152, 8 k-steps, ONE lgkmcnt-only barrier/step, vmcnt never drained,
// depth-2 register prefetch (r6 schedule). Rows 128B, swizzle slot^=(row&7).
// A/B frag (32x32x16): row/col = lane&31, k = 8*(lane>>5)+e  (K=16/sub-step).
// C/D (verified m74/m101): col = lane&31, row = (reg&3)+8*(reg>>2)+4*(lane>>5).
// LDS: A[buf]@buf*16384 (128x64 bf16 16KB), B[buf]@32768+buf*20480 (20KB),
// total 73728 -> 2 blocks/CU. Epilogue: Ct[128][168] @0 + sA @43008 (union).
__global__ __launch_bounds__(256, 2) void gemm_mfma(
    const float* __restrict__ x, const ushort_t* __restrict__ Wt,
    ushort_t* __restrict__ uhat, float* __restrict__ partials) {
  __shared__ __align__(16) char smem[73728];
  const int tid = threadIdx.x;
  const int wid = tid >> 6, lane = tid & 63;
  const int l31 = lane & 31, lh = lane >> 5;
  const int row0 = blockIdx.x * 128;

  float16v acc[5];
#pragma unroll
  for (int nt = 0; nt < 5; ++nt)
#pragma unroll
    for (int r = 0; r < 16; ++r) acc[nt][r] = 0.f;

  // A staging: 4 pieces f = tid + i*256 in [0,1024): row = f>>3 (0..127), slot = f&7
  int aby[4];
#pragma unroll
  for (int i = 0; i < 4; ++i) {
    int f = tid + i * 256;
    int ar = f >> 3, s = f & 7;
    aby[i] = (ar << 7) + ((s ^ (ar & 7)) << 4);
  }
  const int arow_ = tid >> 3;            // row of piece 0 (rows advance by 32/piece)
  const int akq = tid & 7;
  // B staging: 5 pieces f = tid + i*256 in [0,1280): row = f>>3 (0..159), slot = f&7
  int bsrc[5], bby[5];
#pragma unroll
  for (int i = 0; i < 5; ++i) {
    int f = tid + i * 256;
    int br = f >> 3, bs = f & 7;
    bsrc[i] = br * KD + bs * 8;
    bby[i] = (br << 7) + ((bs ^ (br & 7)) << 4);
  }

  float4v rA[4][2];
  short8v rB[5];

  auto LOADS = [&](int ks) {
    int k0 = ks * 64;
#pragma unroll
    for (int i = 0; i < 4; ++i) {
      const float* p = x + (size_t)(row0 + arow_ + i * 32) * KD + k0 + akq * 8;
      rA[i][0] = *reinterpret_cast<const float4v*>(p);
      rA[i][1] = *reinterpret_cast<const float4v*>(p + 4);
    }
#pragma unroll
    for (int i = 0; i < 5; ++i)
      rB[i] = *reinterpret_cast<const short8v*>(Wt + bsrc[i] + k0);
  };
  auto WRITES = [&](int buf) {
    char* Ab = smem + buf * 16384;
    char* Bb = smem + 32768 + buf * 20480;
#pragma unroll
    for (int i = 0; i < 4; ++i) {
      short8v pk;
#pragma unroll
      for (int e = 0; e < 4; ++e) {
        pk[e] = (short)f2bf(rA[i][0][e]);
        pk[e + 4] = (short)f2bf(rA[i][1][e]);
      }
      *reinterpret_cast<short8v*>(Ab + aby[i]) = pk;
    }
#pragma unroll
    for (int i = 0; i < 5; ++i)
      *reinterpret_cast<short8v*>(Bb + bby[i]) = rB[i];
  };

  const int arow = wid * 32 + l31;       // this lane's A row
  const int arx = (arow & 7);
  LOADS(0);
  WRITES(0);
  LOADS(1);
  BAR_LDS();                             // tile 0 visible
  int cur = 0;
  for (int ks = 0; ks < 8; ++ks) {
    const char* Ab = smem + cur * 16384;
    const char* Bb = smem + 32768 + cur * 20480;
#pragma unroll
    for (int ss = 0; ss < 4; ++ss) {     // K=16 sub-steps of BK=64
      int slot = ss * 2 + lh;
      short8v a = *reinterpret_cast<const short8v*>(
          Ab + (arow << 7) + ((slot ^ arx) << 4));
#pragma unroll
      for (int nt = 0; nt < 5; ++nt) {
        int brow = nt * 32 + l31;
        short8v bfr = *reinterpret_cast<const short8v*>(
            Bb + (brow << 7) + ((slot ^ (brow & 7)) << 4));
        acc[nt] = __builtin_amdgcn_mfma_f32_32x32x16_bf16(a, bfr, acc[nt], 0, 0, 0);
      }
    }
    if (ks < 7) {
      WRITES(cur ^ 1);                   // tile ks+1 -> other buf
      if (ks < 6) LOADS(ks + 2);
    }
    BAR_LDS();
    cur ^= 1;
  }

  // ---- passA partials: col-sums over this block's 128 rows
  float* sAf = reinterpret_cast<float*>(smem + 43008);   // [4][160]
#pragma unroll
  for (int nt = 0; nt < 5; ++nt) {
    float p = 0.f;
#pragma unroll
    for (int r = 0; r < 16; ++r) p += acc[nt][r];
    p += __shfl_xor(p, 32);              // combine the two 16-row halves
    if (lh == 0) sAf[wid * CD + nt * 32 + l31] = p;
  }

  // ---- C repack through LDS union -> coalesced 16B stores
  ushort_t* Ct = reinterpret_cast<ushort_t*>(smem);      // [128][168] = 43008 B
#pragma unroll
  for (int nt = 0; nt < 5; ++nt)
#pragma unroll
    for (int r = 0; r < 16; ++r) {
      int row = wid * 32 + (r & 3) + 8 * (r >> 2) + 4 * lh;
      Ct[row * 168 + nt * 32 + l31] = f2bf(acc[nt][r]);
    }
  __syncthreads();
  if (tid < CD) {
    float s = sAf[tid] + sAf[CD + tid] + sAf[2 * CD + tid] + sAf[3 * CD + tid];
    partials[(size_t)blockIdx.x * CD + tid] = s;
  }
#pragma unroll
  for (int i = 0; i < 10; ++i) {
    int p = tid + i * 256;               // 2560 pieces of 16B
    int row = p / 20, c0 = (p % 20) * 8;
    *reinterpret_cast<short8v*>(&uhat[(size_t)(row0 + row) * CD + c0]) =
        *reinterpret_cast<const short8v*>(&Ct[row * 168 + c0]);
  }
}

// ---------- routing iteration with fused v-computation ----------
// vv = v0 = squash(0.1*sum(pg 9 chunks)); ITER2 adds v1 = squash(sum(p1)).
#define ITER_T 640
template <int ITER2>
__global__ __launch_bounds__(ITER_T) void iter_k(
    const ushort_t* __restrict__ uhat, const float* __restrict__ pg,
    const float* __restrict__ p1, float* __restrict__ pout) {
  __shared__ float bv[128][NC];        // 5120 B
  __shared__ float wv[128][NC];        // 5120 B
  __shared__ float sred[32][CD];       // 20480 B
  __shared__ float sred2[4][CD];       // 2560 B
  __shared__ float vv[CD];             // 640 B
  const int blk = blockIdx.x;
  const int b = blk / 9, ch = blk % 9;
  const int t = threadIdx.x;
  const int g = t / 20, q = t % 20;
  const int c = q >> 1;
  const ushort_t* ub = uhat + ((size_t)b * NN + ch * 128) * CD + q * 8;

  // ---- prologue: compute vv (= v0, or v0+v1 for ITER2)
  if (t < CD) {
    float s0 = 0.f;
#pragma unroll
    for (int cc = 0; cc < 9; ++cc) s0 += pg[((size_t)b * 9 + cc) * CD + t];
    s0 *= 0.1f;
    float ss = s0 * s0;
    ss += __shfl_xor(ss, 1); ss += __shfl_xor(ss, 2);
    ss += __shfl_xor(ss, 4); ss += __shfl_xor(ss, 8);
    float sn = sqrtf(ss) + 1e-7f;
    float v = s0 * sn / (1.f + sn * sn);
    if (ITER2) {
      float s1 = 0.f;
#pragma unroll
      for (int cc = 0; cc < 9; ++cc) s1 += p1[((size_t)b * 9 + cc) * CD + t];
      float ss1 = s1 * s1;
      ss1 += __shfl_xor(ss1, 1); ss1 += __shfl_xor(ss1, 2);
      ss1 += __shfl_xor(ss1, 4); ss1 += __shfl_xor(ss1, 8);
      float sn1 = sqrtf(ss1) + 1e-7f;
      v += s1 * sn1 / (1.f + sn1 * sn1);
    }
    vv[t] = v;
  }
  __syncthreads();

  float v0r[8];
  {
    float4v a = *reinterpret_cast<const float4v*>(&vv[q * 8]);
    float4v bb = *reinterpret_cast<const float4v*>(&vv[q * 8 + 4]);
#pragma unroll
    for (int e = 0; e < 4; ++e) { v0r[e] = a[e]; v0r[e + 4] = bb[e]; }
  }

  // ---- phase 1: logits
  short8v u8[4];
#pragma unroll
  for (int it = 0; it < 4; ++it) {
    int n = g + it * 32;
    u8[it] = *reinterpret_cast<const short8v*>(ub + (size_t)n * CD);
    float p = 0.f;
#pragma unroll
    for (int e = 0; e < 8; ++e) p += bf2f((ushort_t)u8[it][e]) * v0r[e];
    p += __shfl_xor(p, 1);
    if ((q & 1) == 0) bv[n][c] = p;
  }
  __syncthreads();

  // ---- phase 1.5: softmax weights once per row
  if (t < 128) {
    float e[NC];
    float bm = bv[t][0];
#pragma unroll
    for (int cc = 1; cc < NC; ++cc) bm = fmaxf(bm, bv[t][cc]);
    float Z = 0.f;
#pragma unroll
    for (int cc = 0; cc < NC; ++cc) { e[cc] = __expf(bv[t][cc] - bm); Z += e[cc]; }
    float rz = 1.f / Z;
#pragma unroll
    for (int cc = 0; cc < NC; ++cc) wv[t][cc] = e[cc] * rz;
  }
  __syncthreads();

  // ---- phase 2: weighted accumulate
  float a[8];
#pragma unroll
  for (int e = 0; e < 8; ++e) a[e] = 0.f;
#pragma unroll
  for (int it = 0; it < 4; ++it) {
    int n = g + it * 32;
    float w = wv[n][c];
#pragma unroll
    for (int e = 0; e < 8; ++e) a[e] += w * bf2f((ushort_t)u8[it][e]);
  }
  {
    float4v lo, hi;
#pragma unroll
    for (int e = 0; e < 4; ++e) { lo[e] = a[e]; hi[e] = a[e + 4]; }
    float4v* dst = reinterpret_cast<float4v*>(&sred[g][q * 8]);
    dst[0] = lo; dst[1] = hi;
  }
  __syncthreads();
  {
    int col = t % CD, part = t / CD;    // 640 = 4 x 160
    float s = 0.f;
#pragma unroll
    for (int g8 = 0; g8 < 8; ++g8) s += sred[part * 8 + g8][col];
    sred2[part][col] = s;
  }
  __syncthreads();
  if (t < CD) {
    pout[(size_t)blk * CD + t] =
        sred2[0][t] + sred2[1][t] + sred2[2][t] + sred2[3][t];
  }
}

// ---------- final squash ----------
__global__ __launch_bounds__(CD) void squash_out(
    const float* __restrict__ p2, float* __restrict__ outp) {
  int b = blockIdx.x, t = threadIdx.x;
  float s = 0.f;
#pragma unroll
  for (int cc = 0; cc < 9; ++cc) s += p2[((size_t)b * 9 + cc) * CD + t];
  float ss = s * s;
  ss += __shfl_xor(ss, 1); ss += __shfl_xor(ss, 2);
  ss += __shfl_xor(ss, 4); ss += __shfl_xor(ss, 8);
  float sn = sqrtf(ss) + 1e-7f;
  outp[(size_t)b * CD + t] = s * sn / (1.f + sn * sn);
}

extern "C" void kernel_launch(void* const* d_in, const int* in_sizes, int n_in,
                              void* d_out, int out_size, void* d_ws, size_t ws_size,
                              hipStream_t stream) {
  const float* x = (const float*)d_in[0];   // [128,1152,512] f32
  const float* W = (const float*)d_in[1];   // [512,160] f32
  float* out = (float*)d_out;               // [128,10,16] f32

  char* ws = (char*)d_ws;
  ushort_t* uhat = (ushort_t*)ws;                          // 47,185,920 B
  ushort_t* Wt   = (ushort_t*)(ws + 47185920);             //    163,840 B
  float*    pg   = (float*)(ws + 47349760);                //    737,280 B  [1152][160]
  float*    p1   = (float*)(ws + 48087040);                //    737,280 B
  float*    p2   = (float*)(ws + 48824320);                //    737,280 B

  wconv<<<320, 256, 0, stream>>>(W, Wt);
  gemm_mfma<<<1152, 256, 0, stream>>>(x, Wt, uhat, pg);
  iter_k<0><<<1152, ITER_T, 0, stream>>>(uhat, pg, nullptr, p1);  // s1 partials
  iter_k<1><<<1152, ITER_T, 0, stream>>>(uhat, pg, p1, p2);       // s2 partials
  squash_out<<<BB, CD, 0, stream>>>(p2, out);                     // out = v2
}